// Round 1
// baseline (1403.348 us; speedup 1.0000x reference)
//
#include <hip/hip_runtime.h>
#include <math.h>

// LegacyVMambaBlock: LN -> GEMM(384->768) -> dwconv3x3 -> 4x EMA scan -> LN ->
// GEMM(768->384)+res -> LN -> GEMM(384->1536)+gelu -> GEMM(1536->384)+res.
// All GEMMs bf16 MFMA (threshold 0.133 absmax is generous; output dominated by
// fp32 residual passthrough). Workspace: 6*65536 f32 stats + two 96MiB bf16
// buffers (~203MB total).

typedef __attribute__((ext_vector_type(8))) short bf16x8;
typedef __attribute__((ext_vector_type(4))) float f32x4;

#define T_TOKENS 65536
#define DMODEL 384
#define DINNER 768
#define DHIDDEN 1536

__device__ __forceinline__ float bf2f(unsigned short u) {
  unsigned int x = ((unsigned int)u) << 16;
  return __builtin_bit_cast(float, x);
}
__device__ __forceinline__ unsigned short f2bf(float f) {
  unsigned int x = __builtin_bit_cast(unsigned int, f);
  x += 0x7fffu + ((x >> 16) & 1u);
  return (unsigned short)(x >> 16);
}

// ---------------- LN stats: one wave per token ----------------
template <int DIM, bool BF16IN>
__global__ __launch_bounds__(256) void ln_stats_kernel(const void* __restrict__ inv,
                                                       float* __restrict__ mu,
                                                       float* __restrict__ rs) {
  int wid = blockIdx.x * 4 + (threadIdx.x >> 6);
  int lane = threadIdx.x & 63;
  float s = 0.f, ss = 0.f;
  if (BF16IN) {
    const unsigned short* row = (const unsigned short*)inv + (size_t)wid * DIM;
#pragma unroll
    for (int k = 0; k < DIM / 64; k++) {
      float v = bf2f(row[lane + k * 64]);
      s += v; ss += v * v;
    }
  } else {
    const float* row = (const float*)inv + (size_t)wid * DIM;
#pragma unroll
    for (int k = 0; k < DIM / 64; k++) {
      float v = row[lane + k * 64];
      s += v; ss += v * v;
    }
  }
#pragma unroll
  for (int off = 32; off > 0; off >>= 1) {
    s += __shfl_xor(s, off);
    ss += __shfl_xor(ss, off);
  }
  if (lane == 0) {
    float m = s * (1.0f / DIM);
    float var = ss * (1.0f / DIM) - m * m;
    mu[wid] = m;
    rs[wid] = rsqrtf(var + 1e-5f);
  }
}

// ---------------- GEMM: C[M,ND] = opA(A[M,KD]) @ W[KD,ND] + bias (+epi) -----
// BM=BN=128, BK=32. 4 waves 2x2, each wave 64x64 = 4x4 frags of 16x16x32 MFMA.
// A staged to LDS with optional fused LayerNorm (mu/rs per row, lg/lb per k),
// fp32->bf16 convert. W (fp32 [KD][ND]) staged transposed as Bs[n][k] bf16.
// EPI: 0 = store bf16 (+bias); 1 = store f32 (+bias+res); 2 = gelu, store bf16.
template <int KD, int ND, bool ABF16, bool FLN, int EPI>
__global__ __launch_bounds__(256) void gemm_kernel(
    const void* __restrict__ Ain, const float* __restrict__ W,
    const float* __restrict__ bias, const float* __restrict__ mu,
    const float* __restrict__ rs, const float* __restrict__ lg,
    const float* __restrict__ lb, const float* res, void* Out) {
  __shared__ unsigned short As[128 * 40];  // 128 rows x 32k, stride 40 (pad)
  __shared__ unsigned short Bs[128 * 40];  // 128 n    x 32k, stride 40 (pad)

  const int tid = threadIdx.x;
  const int tok0 = blockIdx.x * 128;
  const int n0 = blockIdx.y * 128;
  const int lane = tid & 63;
  const int wv = tid >> 6;
  const int wm = wv >> 1, wn = wv & 1;
  const int lrow = lane & 15;
  const int kgrp = lane >> 4;

  f32x4 acc[4][4];
#pragma unroll
  for (int i = 0; i < 4; i++)
#pragma unroll
    for (int j = 0; j < 4; j++) {
      f32x4 z = {0.f, 0.f, 0.f, 0.f};
      acc[i][j] = z;
    }

  // A-staging assignment: each thread loads 16 contiguous k of one row.
  const int arow = tid >> 1;
  const int ahalf = (tid & 1) * 16;
  const int tok = tok0 + arow;
  float lnm = 0.f, lnr = 1.f;
  if constexpr (FLN) { lnm = mu[tok]; lnr = rs[tok]; }

  // B-staging assignment: each thread loads 16 contiguous n of one k row.
  const int bk = tid >> 3;
  const int bn = (tid & 7) * 16;

  for (int kt = 0; kt < KD; kt += 32) {
    // ---- stage A tile ----
    {
      const int kbase = kt + ahalf;
      if constexpr (!ABF16) {
        const float4* ap =
            (const float4*)((const float*)Ain + (size_t)tok * KD + kbase);
#pragma unroll
        for (int q = 0; q < 4; q++) {
          float4 v = ap[q];
          float e[4] = {v.x, v.y, v.z, v.w};
          ushort4 uu;
          unsigned short* up = (unsigned short*)&uu;
#pragma unroll
          for (int j = 0; j < 4; j++) {
            float o = e[j];
            if constexpr (FLN) {
              int kk = kbase + q * 4 + j;
              o = (o - lnm) * lnr * lg[kk] + lb[kk];
            }
            up[j] = f2bf(o);
          }
          *(ushort4*)&As[arow * 40 + ahalf + q * 4] = uu;
        }
      } else {
        const uint4* ap =
            (const uint4*)((const unsigned short*)Ain + (size_t)tok * KD + kbase);
#pragma unroll
        for (int q = 0; q < 2; q++) {
          uint4 u = ap[q];
          unsigned int ww[4] = {u.x, u.y, u.z, u.w};
#pragma unroll
          for (int p = 0; p < 4; p++) {
#pragma unroll
            for (int hl = 0; hl < 2; hl++) {
              unsigned short us = (unsigned short)((ww[p] >> (16 * hl)) & 0xffffu);
              float o = bf2f(us);
              int kk = kbase + q * 8 + p * 2 + hl;
              if constexpr (FLN) o = (o - lnm) * lnr * lg[kk] + lb[kk];
              As[arow * 40 + ahalf + q * 8 + p * 2 + hl] = f2bf(o);
            }
          }
        }
      }
    }
    // ---- stage B tile (transposed: Bs[n][k]) ----
    {
      const float4* wp = (const float4*)(W + (size_t)(kt + bk) * ND + n0 + bn);
#pragma unroll
      for (int q = 0; q < 4; q++) {
        float4 v = wp[q];
        Bs[(bn + q * 4 + 0) * 40 + bk] = f2bf(v.x);
        Bs[(bn + q * 4 + 1) * 40 + bk] = f2bf(v.y);
        Bs[(bn + q * 4 + 2) * 40 + bk] = f2bf(v.z);
        Bs[(bn + q * 4 + 3) * 40 + bk] = f2bf(v.w);
      }
    }
    __syncthreads();
    // ---- MFMA ----
    bf16x8 af[4], bfr[4];
#pragma unroll
    for (int mf = 0; mf < 4; mf++)
      af[mf] = *(const bf16x8*)&As[(wm * 64 + mf * 16 + lrow) * 40 + kgrp * 8];
#pragma unroll
    for (int nf = 0; nf < 4; nf++)
      bfr[nf] = *(const bf16x8*)&Bs[(wn * 64 + nf * 16 + lrow) * 40 + kgrp * 8];
#pragma unroll
    for (int mf = 0; mf < 4; mf++)
#pragma unroll
      for (int nf = 0; nf < 4; nf++)
        acc[mf][nf] = __builtin_amdgcn_mfma_f32_16x16x32_bf16(
            af[mf], bfr[nf], acc[mf][nf], 0, 0, 0);
    __syncthreads();
  }

  // ---- epilogue ----
#pragma unroll
  for (int mf = 0; mf < 4; mf++) {
#pragma unroll
    for (int nf = 0; nf < 4; nf++) {
      const int gcol = n0 + wn * 64 + nf * 16 + lrow;
      const float bv = bias[gcol];
#pragma unroll
      for (int r = 0; r < 4; r++) {
        const int grow = tok0 + wm * 64 + mf * 16 + kgrp * 4 + r;
        float v = acc[mf][nf][r] + bv;
        const size_t idx = (size_t)grow * ND + gcol;
        if constexpr (EPI == 0) {
          ((unsigned short*)Out)[idx] = f2bf(v);
        } else if constexpr (EPI == 1) {
          ((float*)Out)[idx] = v + res[idx];
        } else {
          float gl = 0.5f * v * (1.0f + erff(v * 0.70710678118654752f));
          ((unsigned short*)Out)[idx] = f2bf(gl);
        }
      }
    }
  }
}

// ---------------- depthwise 3x3 conv, SAME, NHWC, C=768 ----------------
__global__ __launch_bounds__(256) void dwconv_kernel(
    const unsigned short* __restrict__ p, const float* __restrict__ kw,
    unsigned short* __restrict__ out) {
  const int c = (blockIdx.x % 3) * 256 + threadIdx.x;
  const int w = blockIdx.x / 3;
  const int h = blockIdx.y;
  const int b = blockIdx.z;
  float acc = 0.f;
#pragma unroll
  for (int dh = 0; dh < 3; dh++) {
    const int hh = h + dh - 1;
    if (hh < 0 || hh > 63) continue;
#pragma unroll
    for (int dw = 0; dw < 3; dw++) {
      const int ww = w + dw - 1;
      if (ww < 0 || ww > 63) continue;
      const size_t idx = ((size_t)((b * 64 + hh) * 64 + ww)) * DINNER + c;
      acc += bf2f(p[idx]) * kw[(dh * 3 + dw) * DINNER + c];
    }
  }
  out[((size_t)((b * 64 + h) * 64 + w)) * DINNER + c] = f2bf(acc);
}

// ---------------- EMA scans: y = 0.6*y + 0.4*x, fwd+bwd in registers -------
// scan_w: out1 = local + 0.25*(lr+rl)
__global__ __launch_bounds__(256) void scan_w_kernel(
    const unsigned short* __restrict__ local, unsigned short* __restrict__ out1) {
  const int c = blockIdx.x * 256 + threadIdx.x;
  const int bh = blockIdx.y;  // b*64 + h
  const size_t base = (size_t)bh * (64 * DINNER) + c;
  float v[64], f[64];
#pragma unroll
  for (int w = 0; w < 64; w++) v[w] = bf2f(local[base + (size_t)w * DINNER]);
  float y = 0.f;
#pragma unroll
  for (int w = 0; w < 64; w++) {
    y = 0.6f * y + 0.4f * v[w];
    f[w] = y;
  }
  y = 0.f;
#pragma unroll
  for (int w = 63; w >= 0; w--) {
    y = 0.6f * y + 0.4f * v[w];
    out1[base + (size_t)w * DINNER] = f2bf(v[w] + 0.25f * (f[w] + y));
  }
}

// scan_h: inout += 0.25*(tb+bt)   (in-place per element)
__global__ __launch_bounds__(256) void scan_h_kernel(
    const unsigned short* __restrict__ local, unsigned short* inout) {
  const int c = blockIdx.x * 256 + threadIdx.x;
  const int bw = blockIdx.y;  // b*64 + w
  const int b = bw >> 6, w = bw & 63;
  const size_t base = ((size_t)b * 64 * 64 + w) * DINNER + c;
  const size_t sh = (size_t)64 * DINNER;
  float v[64], f[64];
#pragma unroll
  for (int h = 0; h < 64; h++) v[h] = bf2f(local[base + h * sh]);
  float y = 0.f;
#pragma unroll
  for (int h = 0; h < 64; h++) {
    y = 0.6f * y + 0.4f * v[h];
    f[h] = y;
  }
  y = 0.f;
#pragma unroll
  for (int h = 63; h >= 0; h--) {
    y = 0.6f * y + 0.4f * v[h];
    const size_t idx = base + h * sh;
    inout[idx] = f2bf(bf2f(inout[idx]) + 0.25f * (f[h] + y));
  }
}

extern "C" void kernel_launch(void* const* d_in, const int* in_sizes, int n_in,
                              void* d_out, int out_size, void* d_ws,
                              size_t ws_size, hipStream_t stream) {
  const float* x = (const float*)d_in[0];
  const float* n1_g = (const float*)d_in[1];
  const float* n1_b = (const float*)d_in[2];
  const float* w_in = (const float*)d_in[3];
  const float* b_in = (const float*)d_in[4];
  const float* k_conv = (const float*)d_in[5];
  const float* on_g = (const float*)d_in[6];
  const float* on_b = (const float*)d_in[7];
  const float* w_out = (const float*)d_in[8];
  const float* b_out = (const float*)d_in[9];
  const float* n2_g = (const float*)d_in[10];
  const float* n2_b = (const float*)d_in[11];
  const float* w1 = (const float*)d_in[12];
  const float* b1 = (const float*)d_in[13];
  const float* w2 = (const float*)d_in[14];
  const float* b2 = (const float*)d_in[15];

  char* ws = (char*)d_ws;
  float* mu1 = (float*)ws;
  float* rs1 = mu1 + T_TOKENS;
  float* muM = rs1 + T_TOKENS;
  float* rsM = muM + T_TOKENS;
  float* mu2 = rsM + T_TOKENS;
  float* rs2 = mu2 + T_TOKENS;
  unsigned short* buf1 = (unsigned short*)(rs2 + T_TOKENS);  // p -> out1 -> mixed
  unsigned short* buf2 = buf1 + (size_t)T_TOKENS * DINNER;   // local
  unsigned short* gbuf = buf1;  // gelu output spans buf1+buf2 (192 MiB)

  float* out = (float*)d_out;
  dim3 b256(256);

  // 1. LN1 stats over x
  ln_stats_kernel<DMODEL, false><<<T_TOKENS / 4, b256, 0, stream>>>(x, mu1, rs1);
  // 2. p = LN1(x) @ w_in + b_in  (bf16)
  gemm_kernel<DMODEL, DINNER, false, true, 0><<<dim3(512, 6), b256, 0, stream>>>(
      x, w_in, b_in, mu1, rs1, n1_g, n1_b, nullptr, buf1);
  // 3. local = dwconv3x3(p)
  dwconv_kernel<<<dim3(192, 64, 16), b256, 0, stream>>>(buf1, k_conv, buf2);
  // 4. out1 = local + 0.25*(lr+rl)   (overwrites p)
  scan_w_kernel<<<dim3(3, 1024), b256, 0, stream>>>(buf2, buf1);
  // 5. mixed = out1 + 0.25*(tb+bt)   (in place)
  scan_h_kernel<<<dim3(3, 1024), b256, 0, stream>>>(buf2, buf1);
  // 6. LN(on) stats over mixed
  ln_stats_kernel<DINNER, true><<<T_TOKENS / 4, b256, 0, stream>>>(buf1, muM, rsM);
  // 7. x2 = x + LN(mixed) @ w_out + b_out  (f32 -> d_out)
  gemm_kernel<DINNER, DMODEL, true, true, 1><<<dim3(512, 3), b256, 0, stream>>>(
      buf1, w_out, b_out, muM, rsM, on_g, on_b, x, out);
  // 8. LN2 stats over x2
  ln_stats_kernel<DMODEL, false><<<T_TOKENS / 4, b256, 0, stream>>>(out, mu2, rs2);
  // 9. g = gelu(LN2(x2) @ w1 + b1)  (bf16, spans buf1+buf2)
  gemm_kernel<DMODEL, DHIDDEN, false, true, 2><<<dim3(512, 12), b256, 0, stream>>>(
      out, w1, b1, mu2, rs2, n2_g, n2_b, nullptr, gbuf);
  // 10. out = x2 + g @ w2 + b2  (in place on d_out)
  gemm_kernel<DHIDDEN, DMODEL, true, false, 1><<<dim3(512, 3), b256, 0, stream>>>(
      gbuf, w2, b2, nullptr, nullptr, nullptr, nullptr, out, out);
}

// Round 2
// 1215.142 us; speedup vs baseline: 1.1549x; 1.1549x over previous
//
#include <hip/hip_runtime.h>
#include <math.h>

// LegacyVMambaBlock: LN -> GEMM(384->768) -> dwconv3x3 -> 4x EMA scan -> LN ->
// GEMM(768->384)+res -> LN -> GEMM(384->1536)+gelu -> GEMM(1536->384)+res.
// R2: vectorized dwconv (uint4 = 8ch/thread), packed-bf16 scans (2ch/thread),
// vectorized ln_stats. GEMMs unchanged from R1.

typedef __attribute__((ext_vector_type(8))) short bf16x8;
typedef __attribute__((ext_vector_type(4))) float f32x4;

#define T_TOKENS 65536
#define DMODEL 384
#define DINNER 768
#define DHIDDEN 1536

__device__ __forceinline__ float bf2f(unsigned short u) {
  unsigned int x = ((unsigned int)u) << 16;
  return __builtin_bit_cast(float, x);
}
__device__ __forceinline__ unsigned short f2bf(float f) {
  unsigned int x = __builtin_bit_cast(unsigned int, f);
  x += 0x7fffu + ((x >> 16) & 1u);
  return (unsigned short)(x >> 16);
}
// packed pair: lo = channel c (low 16 bits), hi = channel c+1 (high 16 bits)
__device__ __forceinline__ void unpack2(unsigned int u, float& lo, float& hi) {
  lo = __builtin_bit_cast(float, u << 16);
  hi = __builtin_bit_cast(float, u & 0xffff0000u);
}
__device__ __forceinline__ unsigned int pack2(float lo, float hi) {
  return (unsigned int)f2bf(lo) | ((unsigned int)f2bf(hi) << 16);
}

// ---------------- LN stats: one wave per token, vectorized ----------------
template <int DIM, bool BF16IN>
__global__ __launch_bounds__(256) void ln_stats_kernel(const void* __restrict__ inv,
                                                       float* __restrict__ mu,
                                                       float* __restrict__ rs) {
  int wid = blockIdx.x * 4 + (threadIdx.x >> 6);
  int lane = threadIdx.x & 63;
  float s = 0.f, ss = 0.f;
  if constexpr (BF16IN) {
    const uint2* row = (const uint2*)((const unsigned short*)inv + (size_t)wid * DIM);
#pragma unroll
    for (int k = 0; k < DIM / 256; k++) {
      uint2 u = row[lane + k * 64];
      float a, b, c, d;
      unpack2(u.x, a, b);
      unpack2(u.y, c, d);
      s += a + b + c + d;
      ss += a * a + b * b + c * c + d * d;
    }
  } else {
    const float2* row = (const float2*)((const float*)inv + (size_t)wid * DIM);
#pragma unroll
    for (int k = 0; k < DIM / 128; k++) {
      float2 v = row[lane + k * 64];
      s += v.x + v.y;
      ss += v.x * v.x + v.y * v.y;
    }
  }
#pragma unroll
  for (int off = 32; off > 0; off >>= 1) {
    s += __shfl_xor(s, off);
    ss += __shfl_xor(ss, off);
  }
  if (lane == 0) {
    float m = s * (1.0f / DIM);
    float var = ss * (1.0f / DIM) - m * m;
    mu[wid] = m;
    rs[wid] = rsqrtf(var + 1e-5f);
  }
}

// ---------------- GEMM (unchanged from R1) ----------------
template <int KD, int ND, bool ABF16, bool FLN, int EPI>
__global__ __launch_bounds__(256) void gemm_kernel(
    const void* __restrict__ Ain, const float* __restrict__ W,
    const float* __restrict__ bias, const float* __restrict__ mu,
    const float* __restrict__ rs, const float* __restrict__ lg,
    const float* __restrict__ lb, const float* res, void* Out) {
  __shared__ unsigned short As[128 * 40];
  __shared__ unsigned short Bs[128 * 40];

  const int tid = threadIdx.x;
  const int tok0 = blockIdx.x * 128;
  const int n0 = blockIdx.y * 128;
  const int lane = tid & 63;
  const int wv = tid >> 6;
  const int wm = wv >> 1, wn = wv & 1;
  const int lrow = lane & 15;
  const int kgrp = lane >> 4;

  f32x4 acc[4][4];
#pragma unroll
  for (int i = 0; i < 4; i++)
#pragma unroll
    for (int j = 0; j < 4; j++) {
      f32x4 z = {0.f, 0.f, 0.f, 0.f};
      acc[i][j] = z;
    }

  const int arow = tid >> 1;
  const int ahalf = (tid & 1) * 16;
  const int tok = tok0 + arow;
  float lnm = 0.f, lnr = 1.f;
  if constexpr (FLN) { lnm = mu[tok]; lnr = rs[tok]; }

  const int bk = tid >> 3;
  const int bn = (tid & 7) * 16;

  for (int kt = 0; kt < KD; kt += 32) {
    {
      const int kbase = kt + ahalf;
      if constexpr (!ABF16) {
        const float4* ap =
            (const float4*)((const float*)Ain + (size_t)tok * KD + kbase);
#pragma unroll
        for (int q = 0; q < 4; q++) {
          float4 v = ap[q];
          float e[4] = {v.x, v.y, v.z, v.w};
          ushort4 uu;
          unsigned short* up = (unsigned short*)&uu;
#pragma unroll
          for (int j = 0; j < 4; j++) {
            float o = e[j];
            if constexpr (FLN) {
              int kk = kbase + q * 4 + j;
              o = (o - lnm) * lnr * lg[kk] + lb[kk];
            }
            up[j] = f2bf(o);
          }
          *(ushort4*)&As[arow * 40 + ahalf + q * 4] = uu;
        }
      } else {
        const uint4* ap =
            (const uint4*)((const unsigned short*)Ain + (size_t)tok * KD + kbase);
#pragma unroll
        for (int q = 0; q < 2; q++) {
          uint4 u = ap[q];
          unsigned int ww[4] = {u.x, u.y, u.z, u.w};
#pragma unroll
          for (int p = 0; p < 4; p++) {
#pragma unroll
            for (int hl = 0; hl < 2; hl++) {
              unsigned short us = (unsigned short)((ww[p] >> (16 * hl)) & 0xffffu);
              float o = bf2f(us);
              int kk = kbase + q * 8 + p * 2 + hl;
              if constexpr (FLN) o = (o - lnm) * lnr * lg[kk] + lb[kk];
              As[arow * 40 + ahalf + q * 8 + p * 2 + hl] = f2bf(o);
            }
          }
        }
      }
    }
    {
      const float4* wp = (const float4*)(W + (size_t)(kt + bk) * ND + n0 + bn);
#pragma unroll
      for (int q = 0; q < 4; q++) {
        float4 v = wp[q];
        Bs[(bn + q * 4 + 0) * 40 + bk] = f2bf(v.x);
        Bs[(bn + q * 4 + 1) * 40 + bk] = f2bf(v.y);
        Bs[(bn + q * 4 + 2) * 40 + bk] = f2bf(v.z);
        Bs[(bn + q * 4 + 3) * 40 + bk] = f2bf(v.w);
      }
    }
    __syncthreads();
    bf16x8 af[4], bfr[4];
#pragma unroll
    for (int mf = 0; mf < 4; mf++)
      af[mf] = *(const bf16x8*)&As[(wm * 64 + mf * 16 + lrow) * 40 + kgrp * 8];
#pragma unroll
    for (int nf = 0; nf < 4; nf++)
      bfr[nf] = *(const bf16x8*)&Bs[(wn * 64 + nf * 16 + lrow) * 40 + kgrp * 8];
#pragma unroll
    for (int mf = 0; mf < 4; mf++)
#pragma unroll
      for (int nf = 0; nf < 4; nf++)
        acc[mf][nf] = __builtin_amdgcn_mfma_f32_16x16x32_bf16(
            af[mf], bfr[nf], acc[mf][nf], 0, 0, 0);
    __syncthreads();
  }

#pragma unroll
  for (int mf = 0; mf < 4; mf++) {
#pragma unroll
    for (int nf = 0; nf < 4; nf++) {
      const int gcol = n0 + wn * 64 + nf * 16 + lrow;
      const float bv = bias[gcol];
#pragma unroll
      for (int r = 0; r < 4; r++) {
        const int grow = tok0 + wm * 64 + mf * 16 + kgrp * 4 + r;
        float v = acc[mf][nf][r] + bv;
        const size_t idx = (size_t)grow * ND + gcol;
        if constexpr (EPI == 0) {
          ((unsigned short*)Out)[idx] = f2bf(v);
        } else if constexpr (EPI == 1) {
          ((float*)Out)[idx] = v + res[idx];
        } else {
          float gl = 0.5f * v * (1.0f + erff(v * 0.70710678118654752f));
          ((unsigned short*)Out)[idx] = f2bf(gl);
        }
      }
    }
  }
}

// ---------------- depthwise 3x3 conv, vectorized: 8 ch/thread ----------------
__global__ __launch_bounds__(256) void dwconv_kernel(
    const unsigned short* __restrict__ p, const float* __restrict__ kw,
    unsigned short* __restrict__ out) {
  const int u = blockIdx.x * 256 + threadIdx.x;  // 65536*96 units
  const int cg = u % 96;
  const int pos = u / 96;  // (b*64+h)*64+w
  const int c = cg * 8;
  const int w = pos & 63;
  const int h = (pos >> 6) & 63;
  const int b = pos >> 12;

  float acc[8];
#pragma unroll
  for (int j = 0; j < 8; j++) acc[j] = 0.f;

#pragma unroll
  for (int dh = 0; dh < 3; dh++) {
    const int hh = h + dh - 1;
    const bool vh = (unsigned)hh < 64u;
    const int hcl = min(max(hh, 0), 63);
    const size_t rb = ((size_t)((b << 12) + (hcl << 6))) * DINNER + c;
#pragma unroll
    for (int dw = 0; dw < 3; dw++) {
      const int ww = w + dw - 1;
      const bool vv = vh && ((unsigned)ww < 64u);
      const int wcl = min(max(ww, 0), 63);
      uint4 pv = *(const uint4*)(p + rb + (size_t)wcl * DINNER);
      if (!vv) { pv.x = 0; pv.y = 0; pv.z = 0; pv.w = 0; }
      const float4 k0 = *(const float4*)(kw + (dh * 3 + dw) * DINNER + c);
      const float4 k1 = *(const float4*)(kw + (dh * 3 + dw) * DINNER + c + 4);
      float lo, hi;
      unpack2(pv.x, lo, hi); acc[0] += lo * k0.x; acc[1] += hi * k0.y;
      unpack2(pv.y, lo, hi); acc[2] += lo * k0.z; acc[3] += hi * k0.w;
      unpack2(pv.z, lo, hi); acc[4] += lo * k1.x; acc[5] += hi * k1.y;
      unpack2(pv.w, lo, hi); acc[6] += lo * k1.z; acc[7] += hi * k1.w;
    }
  }
  uint4 st;
  st.x = pack2(acc[0], acc[1]);
  st.y = pack2(acc[2], acc[3]);
  st.z = pack2(acc[4], acc[5]);
  st.w = pack2(acc[6], acc[7]);
  *(uint4*)(out + (size_t)pos * DINNER + c) = st;
}

// ---------------- EMA scans: 2 ch/thread, packed-bf16 register arrays -------
// scan_w: out1 = local + 0.25*(lr+rl)
__global__ __launch_bounds__(128) void scan_w_kernel(
    const unsigned short* __restrict__ local, unsigned short* __restrict__ out1) {
  const int c2 = blockIdx.x * 128 + threadIdx.x;  // 0..383 channel-pairs
  const int bh = blockIdx.y;                      // b*64 + h
  const unsigned int* lp = (const unsigned int*)(local + (size_t)bh * 64 * DINNER) + c2;
  unsigned int* op = (unsigned int*)(out1 + (size_t)bh * 64 * DINNER) + c2;
  unsigned int v2[64], f2[64];
#pragma unroll
  for (int w = 0; w < 64; w++) v2[w] = lp[w * (DINNER / 2)];
  float ya = 0.f, yb = 0.f;
#pragma unroll
  for (int w = 0; w < 64; w++) {
    float a, b;
    unpack2(v2[w], a, b);
    ya = 0.6f * ya + 0.4f * a;
    yb = 0.6f * yb + 0.4f * b;
    f2[w] = pack2(ya, yb);
  }
  ya = 0.f; yb = 0.f;
#pragma unroll
  for (int w = 63; w >= 0; w--) {
    float a, b, fa, fb;
    unpack2(v2[w], a, b);
    ya = 0.6f * ya + 0.4f * a;
    yb = 0.6f * yb + 0.4f * b;
    unpack2(f2[w], fa, fb);
    op[w * (DINNER / 2)] = pack2(a + 0.25f * (fa + ya), b + 0.25f * (fb + yb));
  }
}

// scan_h: inout += 0.25*(tb+bt)
__global__ __launch_bounds__(128) void scan_h_kernel(
    const unsigned short* __restrict__ local, unsigned short* inout) {
  const int c2 = blockIdx.x * 128 + threadIdx.x;
  const int bw = blockIdx.y;  // b*64 + w
  const int b = bw >> 6, w = bw & 63;
  const unsigned int base = (unsigned int)(b * 4096 + w) * (DINNER / 2) + c2;
  const unsigned int sh = 64 * (DINNER / 2);
  const unsigned int* lp = (const unsigned int*)local + base;
  unsigned int* io = (unsigned int*)inout + base;
  unsigned int v2[64], f2[64];
#pragma unroll
  for (int h = 0; h < 64; h++) v2[h] = lp[h * sh];
  float ya = 0.f, yb = 0.f;
#pragma unroll
  for (int h = 0; h < 64; h++) {
    float a, b;
    unpack2(v2[h], a, b);
    ya = 0.6f * ya + 0.4f * a;
    yb = 0.6f * yb + 0.4f * b;
    f2[h] = pack2(ya, yb);
  }
  ya = 0.f; yb = 0.f;
#pragma unroll
  for (int h = 63; h >= 0; h--) {
    float a, b, fa, fb, oa, ob;
    unpack2(v2[h], a, b);
    ya = 0.6f * ya + 0.4f * a;
    yb = 0.6f * yb + 0.4f * b;
    unpack2(f2[h], fa, fb);
    unpack2(io[h * sh], oa, ob);
    io[h * sh] = pack2(oa + 0.25f * (fa + ya), ob + 0.25f * (fb + yb));
  }
}

extern "C" void kernel_launch(void* const* d_in, const int* in_sizes, int n_in,
                              void* d_out, int out_size, void* d_ws,
                              size_t ws_size, hipStream_t stream) {
  const float* x = (const float*)d_in[0];
  const float* n1_g = (const float*)d_in[1];
  const float* n1_b = (const float*)d_in[2];
  const float* w_in = (const float*)d_in[3];
  const float* b_in = (const float*)d_in[4];
  const float* k_conv = (const float*)d_in[5];
  const float* on_g = (const float*)d_in[6];
  const float* on_b = (const float*)d_in[7];
  const float* w_out = (const float*)d_in[8];
  const float* b_out = (const float*)d_in[9];
  const float* n2_g = (const float*)d_in[10];
  const float* n2_b = (const float*)d_in[11];
  const float* w1 = (const float*)d_in[12];
  const float* b1 = (const float*)d_in[13];
  const float* w2 = (const float*)d_in[14];
  const float* b2 = (const float*)d_in[15];

  char* ws = (char*)d_ws;
  float* mu1 = (float*)ws;
  float* rs1 = mu1 + T_TOKENS;
  float* muM = rs1 + T_TOKENS;
  float* rsM = muM + T_TOKENS;
  float* mu2 = rsM + T_TOKENS;
  float* rs2 = mu2 + T_TOKENS;
  unsigned short* buf1 = (unsigned short*)(rs2 + T_TOKENS);  // p -> out1 -> mixed
  unsigned short* buf2 = buf1 + (size_t)T_TOKENS * DINNER;   // local
  unsigned short* gbuf = buf1;  // gelu output spans buf1+buf2 (192 MiB)

  float* out = (float*)d_out;
  dim3 b256(256);

  // 1. LN1 stats over x
  ln_stats_kernel<DMODEL, false><<<T_TOKENS / 4, b256, 0, stream>>>(x, mu1, rs1);
  // 2. p = LN1(x) @ w_in + b_in  (bf16)
  gemm_kernel<DMODEL, DINNER, false, true, 0><<<dim3(512, 6), b256, 0, stream>>>(
      x, w_in, b_in, mu1, rs1, n1_g, n1_b, nullptr, buf1);
  // 3. local = dwconv3x3(p)
  dwconv_kernel<<<dim3(T_TOKENS * 96 / 256), b256, 0, stream>>>(buf1, k_conv, buf2);
  // 4. out1 = local + 0.25*(lr+rl)
  scan_w_kernel<<<dim3(3, 1024), dim3(128), 0, stream>>>(buf2, buf1);
  // 5. mixed = out1 + 0.25*(tb+bt)
  scan_h_kernel<<<dim3(3, 1024), dim3(128), 0, stream>>>(buf2, buf1);
  // 6. LN(on) stats over mixed
  ln_stats_kernel<DINNER, true><<<T_TOKENS / 4, b256, 0, stream>>>(buf1, muM, rsM);
  // 7. x2 = x + LN(mixed) @ w_out + b_out  (f32 -> d_out)
  gemm_kernel<DINNER, DMODEL, true, true, 1><<<dim3(512, 3), b256, 0, stream>>>(
      buf1, w_out, b_out, muM, rsM, on_g, on_b, x, out);
  // 8. LN2 stats over x2
  ln_stats_kernel<DMODEL, false><<<T_TOKENS / 4, b256, 0, stream>>>(out, mu2, rs2);
  // 9. g = gelu(LN2(x2) @ w1 + b1)  (bf16)
  gemm_kernel<DMODEL, DHIDDEN, false, true, 2><<<dim3(512, 12), b256, 0, stream>>>(
      out, w1, b1, mu2, rs2, n2_g, n2_b, nullptr, gbuf);
  // 10. out = x2 + g @ w2 + b2  (in place on d_out)
  gemm_kernel<DHIDDEN, DMODEL, true, false, 1><<<dim3(512, 3), b256, 0, stream>>>(
      gbuf, w2, b2, nullptr, nullptr, nullptr, nullptr, out, out);
}

// Round 3
// 798.378 us; speedup vs baseline: 1.7577x; 1.5220x over previous
//
#include <hip/hip_runtime.h>
#include <math.h>

// LegacyVMambaBlock R3: all GEMMs pure-bf16 m97-style (128x128xBK64, 4 waves,
// global_load_lds w=16, XOR swizzle (row&7)<<4 both-sides). Weights pre-
// transposed to bf16 [N][K]; LN done as fused one-wave-per-token pass writing
// bf16 A. MLP split into two halves to fit 193.5MB workspace.

typedef __attribute__((ext_vector_type(8))) short bf16x8;
typedef __attribute__((ext_vector_type(4))) float f32x4;

#define T_TOKENS 65536
#define DMODEL 384
#define DINNER 768
#define DHIDDEN 1536

__device__ __forceinline__ float bf2f(unsigned short u) {
  unsigned int x = ((unsigned int)u) << 16;
  return __builtin_bit_cast(float, x);
}
__device__ __forceinline__ unsigned short f2bf(float f) {
  unsigned int x = __builtin_bit_cast(unsigned int, f);
  x += 0x7fffu + ((x >> 16) & 1u);
  return (unsigned short)(x >> 16);
}
__device__ __forceinline__ void unpack2(unsigned int u, float& lo, float& hi) {
  lo = __builtin_bit_cast(float, u << 16);
  hi = __builtin_bit_cast(float, u & 0xffff0000u);
}
__device__ __forceinline__ unsigned int pack2(float lo, float hi) {
  return (unsigned int)f2bf(lo) | ((unsigned int)f2bf(hi) << 16);
}

__device__ __forceinline__ void gload16(const void* g, void* l) {
  __builtin_amdgcn_global_load_lds(
      (const __attribute__((address_space(1))) void*)g,
      (__attribute__((address_space(3))) void*)l, 16, 0, 0);
}

// ---------- fused LN (stats + normalize + bf16 store), one wave per token ----
__global__ __launch_bounds__(256) void ln_fused_f32_384(
    const float* __restrict__ in, const float* __restrict__ g,
    const float* __restrict__ b, unsigned short* __restrict__ out) {
  const int tok = blockIdx.x * 4 + (threadIdx.x >> 6);
  const int lane = threadIdx.x & 63;
  const float2* row = (const float2*)(in + (size_t)tok * 384);
  float2 v[3];
  float s = 0.f, ss = 0.f;
#pragma unroll
  for (int k = 0; k < 3; k++) {
    v[k] = row[lane + 64 * k];
    s += v[k].x + v[k].y;
    ss += v[k].x * v[k].x + v[k].y * v[k].y;
  }
#pragma unroll
  for (int off = 32; off > 0; off >>= 1) {
    s += __shfl_xor(s, off);
    ss += __shfl_xor(ss, off);
  }
  const float m = s * (1.0f / 384.0f);
  const float r = rsqrtf(ss * (1.0f / 384.0f) - m * m + 1e-5f);
  unsigned int* op = (unsigned int*)(out + (size_t)tok * 384);
#pragma unroll
  for (int k = 0; k < 3; k++) {
    const int c = lane + 64 * k;
    const float2 gg = ((const float2*)g)[c];
    const float2 bb = ((const float2*)b)[c];
    op[c] = pack2((v[k].x - m) * r * gg.x + bb.x, (v[k].y - m) * r * gg.y + bb.y);
  }
}

__global__ __launch_bounds__(256) void ln_fused_bf16_768(
    const unsigned short* __restrict__ in, const float* __restrict__ g,
    const float* __restrict__ b, unsigned short* __restrict__ out) {
  const int tok = blockIdx.x * 4 + (threadIdx.x >> 6);
  const int lane = threadIdx.x & 63;
  const uint2* row = (const uint2*)(in + (size_t)tok * 768);
  uint2 u[3];
  float s = 0.f, ss = 0.f;
  float e[3][4];
#pragma unroll
  for (int k = 0; k < 3; k++) {
    u[k] = row[lane + 64 * k];
    unpack2(u[k].x, e[k][0], e[k][1]);
    unpack2(u[k].y, e[k][2], e[k][3]);
#pragma unroll
    for (int j = 0; j < 4; j++) {
      s += e[k][j];
      ss += e[k][j] * e[k][j];
    }
  }
#pragma unroll
  for (int off = 32; off > 0; off >>= 1) {
    s += __shfl_xor(s, off);
    ss += __shfl_xor(ss, off);
  }
  const float m = s * (1.0f / 768.0f);
  const float r = rsqrtf(ss * (1.0f / 768.0f) - m * m + 1e-5f);
  uint2* op = (uint2*)(out + (size_t)tok * 768);
#pragma unroll
  for (int k = 0; k < 3; k++) {
    const int c = lane + 64 * k;
    const float4 gg = ((const float4*)g)[c];
    const float4 bb = ((const float4*)b)[c];
    uint2 w;
    w.x = pack2((e[k][0] - m) * r * gg.x + bb.x, (e[k][1] - m) * r * gg.y + bb.y);
    w.y = pack2((e[k][2] - m) * r * gg.z + bb.z, (e[k][3] - m) * r * gg.w + bb.w);
    op[c] = w;
  }
}

// ---------- weight prep: f32 [K,N] -> bf16 [N,K] (32x32 LDS transpose) ------
__global__ __launch_bounds__(256) void wprep_kernel(const float* __restrict__ in,
                                                    unsigned short* __restrict__ out,
                                                    int K, int N) {
  __shared__ float t[32][33];
  const int k0 = blockIdx.x * 32, n0 = blockIdx.y * 32;
  const int a = threadIdx.x & 31, b8 = threadIdx.x >> 5;  // a: 0..31, b8: 0..7
#pragma unroll
  for (int i = 0; i < 4; i++)
    t[b8 + 8 * i][a] = in[(size_t)(k0 + b8 + 8 * i) * N + n0 + a];
  __syncthreads();
#pragma unroll
  for (int i = 0; i < 4; i++)
    out[(size_t)(n0 + b8 + 8 * i) * K + k0 + a] = f2bf(t[a][b8 + 8 * i]);
}

// ---------- GEMM: C[M,:] = A[M,KT]bf16 @ Bt[N,KT]bf16^T + bias (+epi) -------
// BM=BN=128, BK=64, 4 waves 2x2 (64x64 each). global_load_lds w=16 staging,
// XOR swizzle phys = logical ^ ((row&7)<<4), linear LDS dest + inverse-
// swizzled global source + swizzled ds_read_b128 (rule 21).
// EPI: 0 = bf16 store (+bias); 1 = f32 store (+bias+res); 2 = gelu bf16 store.
template <int EPI>
__global__ __launch_bounds__(256) void gemm_bt_kernel(
    const unsigned short* __restrict__ A, int lda,
    const unsigned short* __restrict__ Bt, int ldb, int k0, int KT,
    const float* __restrict__ bias, const float* __restrict__ res,
    void* __restrict__ C, int ldc, int nby) {
  __shared__ unsigned short As[8192];  // 128 rows x 64 k, 16KB, swizzled
  __shared__ unsigned short Bs[8192];

  const int tid = threadIdx.x;
  const int w = tid >> 6, lane = tid & 63;
  // XCD-chunked bijective swizzle (gridDim.x % 8 == 0 for all our launches)
  const int cpx = gridDim.x >> 3;
  const int g = blockIdx.x;
  const int sw = (g & 7) * cpx + (g >> 3);
  const int bx = sw / nby, by = sw - bx * nby;
  const int tok0 = bx << 7, n0 = by << 7;

  const int wm = w >> 1, wn = w & 1;
  const int lrow = lane & 15, kgrp = lane >> 4;
  const int cx = lrow & 7;  // read-side chunk XOR

  // staging: inst i covers LDS bytes [(w*4+i)*1024, +1024), lane covers 16B.
  // physical p = inst*1024 + 16*lane -> row = inst*8 + (lane>>3),
  // chunk = (lane&7) ^ (row&7) = (lane&7) ^ ((lane>>3)&7).
  const int lr8 = lane >> 3;
  const int kce = ((lane & 7) ^ lr8) << 3;  // k element offset 0..56
  const unsigned short* Abase = A + (size_t)(tok0 + w * 32 + lr8) * lda + kce;
  const unsigned short* Bbase =
      Bt + (size_t)(n0 + w * 32 + lr8) * ldb + (size_t)k0 + kce;

  f32x4 acc[4][4];
#pragma unroll
  for (int i = 0; i < 4; i++)
#pragma unroll
    for (int j = 0; j < 4; j++) {
      f32x4 z = {0.f, 0.f, 0.f, 0.f};
      acc[i][j] = z;
    }

  for (int kt = 0; kt < KT; kt += 64) {
#pragma unroll
    for (int i = 0; i < 4; i++)
      gload16(Abase + (size_t)i * 8 * lda + kt, (char*)As + (w * 4 + i) * 1024);
#pragma unroll
    for (int i = 0; i < 4; i++)
      gload16(Bbase + (size_t)i * 8 * ldb + kt, (char*)Bs + (w * 4 + i) * 1024);
    __syncthreads();

    bf16x8 af[2][4], bf_[2][4];
#pragma unroll
    for (int ks = 0; ks < 2; ks++) {
#pragma unroll
      for (int f = 0; f < 4; f++) {
        const int co = ((ks * 4 + kgrp) ^ cx) << 4;
        af[ks][f] =
            *(const bf16x8*)((const char*)As + (wm * 64 + f * 16 + lrow) * 128 + co);
        bf_[ks][f] =
            *(const bf16x8*)((const char*)Bs + (wn * 64 + f * 16 + lrow) * 128 + co);
      }
    }
#pragma unroll
    for (int ks = 0; ks < 2; ks++)
#pragma unroll
      for (int mf = 0; mf < 4; mf++)
#pragma unroll
        for (int nf = 0; nf < 4; nf++)
          acc[mf][nf] = __builtin_amdgcn_mfma_f32_16x16x32_bf16(
              af[ks][mf], bf_[ks][nf], acc[mf][nf], 0, 0, 0);
    __syncthreads();
  }

#pragma unroll
  for (int mf = 0; mf < 4; mf++) {
#pragma unroll
    for (int nf = 0; nf < 4; nf++) {
      const int gcol = n0 + wn * 64 + nf * 16 + lrow;
      const float bv = bias ? bias[gcol] : 0.0f;
#pragma unroll
      for (int r = 0; r < 4; r++) {
        const int grow = tok0 + wm * 64 + mf * 16 + kgrp * 4 + r;
        float v = acc[mf][nf][r] + bv;
        const size_t idx = (size_t)grow * ldc + gcol;
        if constexpr (EPI == 0) {
          ((unsigned short*)C)[idx] = f2bf(v);
        } else if constexpr (EPI == 1) {
          ((float*)C)[idx] = v + res[idx];
        } else {
          ((unsigned short*)C)[idx] =
              f2bf(0.5f * v * (1.0f + erff(v * 0.70710678118654752f)));
        }
      }
    }
  }
}

// ---------- depthwise 3x3 conv, 8 ch/thread ----------
__global__ __launch_bounds__(256) void dwconv_kernel(
    const unsigned short* __restrict__ p, const float* __restrict__ kw,
    unsigned short* __restrict__ out) {
  const int u = blockIdx.x * 256 + threadIdx.x;
  const int cg = u % 96;
  const int pos = u / 96;
  const int c = cg * 8;
  const int w = pos & 63;
  const int h = (pos >> 6) & 63;
  const int b = pos >> 12;

  float acc[8];
#pragma unroll
  for (int j = 0; j < 8; j++) acc[j] = 0.f;

#pragma unroll
  for (int dh = 0; dh < 3; dh++) {
    const int hh = h + dh - 1;
    const bool vh = (unsigned)hh < 64u;
    const int hcl = min(max(hh, 0), 63);
    const size_t rb = ((size_t)((b << 12) + (hcl << 6))) * DINNER + c;
#pragma unroll
    for (int dw = 0; dw < 3; dw++) {
      const int ww = w + dw - 1;
      const bool vv = vh && ((unsigned)ww < 64u);
      const int wcl = min(max(ww, 0), 63);
      uint4 pv = *(const uint4*)(p + rb + (size_t)wcl * DINNER);
      if (!vv) { pv.x = 0; pv.y = 0; pv.z = 0; pv.w = 0; }
      const float4 k0 = *(const float4*)(kw + (dh * 3 + dw) * DINNER + c);
      const float4 k1 = *(const float4*)(kw + (dh * 3 + dw) * DINNER + c + 4);
      float lo, hi;
      unpack2(pv.x, lo, hi); acc[0] += lo * k0.x; acc[1] += hi * k0.y;
      unpack2(pv.y, lo, hi); acc[2] += lo * k0.z; acc[3] += hi * k0.w;
      unpack2(pv.z, lo, hi); acc[4] += lo * k1.x; acc[5] += hi * k1.y;
      unpack2(pv.w, lo, hi); acc[6] += lo * k1.z; acc[7] += hi * k1.w;
    }
  }
  uint4 st;
  st.x = pack2(acc[0], acc[1]);
  st.y = pack2(acc[2], acc[3]);
  st.z = pack2(acc[4], acc[5]);
  st.w = pack2(acc[6], acc[7]);
  *(uint4*)(out + (size_t)pos * DINNER + c) = st;
}

// ---------- EMA scans ----------
__global__ __launch_bounds__(128) void scan_w_kernel(
    const unsigned short* __restrict__ local, unsigned short* __restrict__ out1) {
  const int c2 = blockIdx.x * 128 + threadIdx.x;
  const int bh = blockIdx.y;
  const unsigned int* lp = (const unsigned int*)(local + (size_t)bh * 64 * DINNER) + c2;
  unsigned int* op = (unsigned int*)(out1 + (size_t)bh * 64 * DINNER) + c2;
  unsigned int v2[64], f2[64];
#pragma unroll
  for (int w = 0; w < 64; w++) v2[w] = lp[w * (DINNER / 2)];
  float ya = 0.f, yb = 0.f;
#pragma unroll
  for (int w = 0; w < 64; w++) {
    float a, b;
    unpack2(v2[w], a, b);
    ya = 0.6f * ya + 0.4f * a;
    yb = 0.6f * yb + 0.4f * b;
    f2[w] = pack2(ya, yb);
  }
  ya = 0.f; yb = 0.f;
#pragma unroll
  for (int w = 63; w >= 0; w--) {
    float a, b, fa, fb;
    unpack2(v2[w], a, b);
    ya = 0.6f * ya + 0.4f * a;
    yb = 0.6f * yb + 0.4f * b;
    unpack2(f2[w], fa, fb);
    op[w * (DINNER / 2)] = pack2(a + 0.25f * (fa + ya), b + 0.25f * (fb + yb));
  }
}

__global__ __launch_bounds__(128) void scan_h_kernel(
    const unsigned short* __restrict__ local, unsigned short* inout) {
  const int c2 = blockIdx.x * 128 + threadIdx.x;
  const int bw = blockIdx.y;
  const int b = bw >> 6, w = bw & 63;
  const unsigned int base = (unsigned int)(b * 4096 + w) * (DINNER / 2) + c2;
  const unsigned int sh = 64 * (DINNER / 2);
  const unsigned int* lp = (const unsigned int*)local + base;
  unsigned int* io = (unsigned int*)inout + base;
  unsigned int v2[64], f2[64];
#pragma unroll
  for (int h = 0; h < 64; h++) v2[h] = lp[h * sh];
  float ya = 0.f, yb = 0.f;
#pragma unroll
  for (int h = 0; h < 64; h++) {
    float a, b;
    unpack2(v2[h], a, b);
    ya = 0.6f * ya + 0.4f * a;
    yb = 0.6f * yb + 0.4f * b;
    f2[h] = pack2(ya, yb);
  }
  ya = 0.f; yb = 0.f;
#pragma unroll
  for (int h = 63; h >= 0; h--) {
    float a, b, fa, fb, oa, ob;
    unpack2(v2[h], a, b);
    ya = 0.6f * ya + 0.4f * a;
    yb = 0.6f * yb + 0.4f * b;
    unpack2(f2[h], fa, fb);
    unpack2(io[h * sh], oa, ob);
    io[h * sh] = pack2(oa + 0.25f * (fa + ya), ob + 0.25f * (fb + yb));
  }
}

extern "C" void kernel_launch(void* const* d_in, const int* in_sizes, int n_in,
                              void* d_out, int out_size, void* d_ws,
                              size_t ws_size, hipStream_t stream) {
  const float* x = (const float*)d_in[0];
  const float* n1_g = (const float*)d_in[1];
  const float* n1_b = (const float*)d_in[2];
  const float* w_in = (const float*)d_in[3];
  const float* b_in = (const float*)d_in[4];
  const float* k_conv = (const float*)d_in[5];
  const float* on_g = (const float*)d_in[6];
  const float* on_b = (const float*)d_in[7];
  const float* w_out = (const float*)d_in[8];
  const float* b_out = (const float*)d_in[9];
  const float* n2_g = (const float*)d_in[10];
  const float* n2_b = (const float*)d_in[11];
  const float* w1 = (const float*)d_in[12];
  const float* b1 = (const float*)d_in[13];
  const float* w2 = (const float*)d_in[14];
  const float* b2 = (const float*)d_in[15];

  const size_t MB = 1024 * 1024;
  char* ws = (char*)d_ws;
  // proven-safe layout: 1.5MB (reserved) + R1 96MB + R2 96MB = 193.5MB
  unsigned short* R1 = (unsigned short*)(ws + 3 * MB / 2);
  unsigned short* R2 = (unsigned short*)(ws + 3 * MB / 2 + 96 * MB);

  unsigned short* A1 = R2;                        // 48MB
  unsigned short* wTin = R2 + (48 * MB) / 2;      // [768][384] 0.56MB
  unsigned short* p = R1;                         // 96MB
  unsigned short* local = R2;                     // 96MB (A1,wTin dead)
  unsigned short* mixed = R1;                     // overwrites p
  unsigned short* A2 = R2;                        // 96MB (local dead)
  unsigned short* wTout = R1;                     // [384][768] 0.56MB (mixed dead)
  unsigned short* A3 = R1;                        // 48MB (wTout dead after G2)
  unsigned short* wT1 = R1 + (48 * MB) / 2;       // [1536][384] 1.125MB
  unsigned short* wT2 = wT1 + (size_t)1536 * 384; // [384][1536] 1.125MB
  unsigned short* gb = R2;                        // 96MB half-hidden buffer

  float* out = (float*)d_out;
  dim3 b256(256);

  // LN1(x) -> A1 bf16
  ln_fused_f32_384<<<T_TOKENS / 4, b256, 0, stream>>>(x, n1_g, n1_b, A1);
  // w_in^T bf16
  wprep_kernel<<<dim3(12, 24), b256, 0, stream>>>(w_in, wTin, DMODEL, DINNER);
  // p = A1 @ w_in + b_in  (bf16)
  gemm_bt_kernel<0><<<3072, b256, 0, stream>>>(A1, DMODEL, wTin, DMODEL, 0, DMODEL,
                                               b_in, nullptr, p, DINNER, 6);
  // local = dwconv3x3(p)
  dwconv_kernel<<<T_TOKENS * 96 / 256, b256, 0, stream>>>(p, k_conv, local);
  // mixed = local + 0.25*(lr+rl)  (overwrites p)
  scan_w_kernel<<<dim3(3, 1024), dim3(128), 0, stream>>>(local, mixed);
  // mixed += 0.25*(tb+bt)
  scan_h_kernel<<<dim3(3, 1024), dim3(128), 0, stream>>>(local, mixed);
  // LN(on)(mixed) -> A2 bf16
  ln_fused_bf16_768<<<T_TOKENS / 4, b256, 0, stream>>>(mixed, on_g, on_b, A2);
  // w_out^T bf16
  wprep_kernel<<<dim3(24, 12), b256, 0, stream>>>(w_out, wTout, DINNER, DMODEL);
  // out = x + A2 @ w_out + b_out  (f32)
  gemm_bt_kernel<1><<<1536, b256, 0, stream>>>(A2, DINNER, wTout, DINNER, 0, DINNER,
                                               b_out, x, out, DMODEL, 3);
  // LN2(out) -> A3 bf16
  ln_fused_f32_384<<<T_TOKENS / 4, b256, 0, stream>>>(out, n2_g, n2_b, A3);
  // w1^T, w2^T bf16
  wprep_kernel<<<dim3(12, 48), b256, 0, stream>>>(w1, wT1, DMODEL, DHIDDEN);
  wprep_kernel<<<dim3(48, 12), b256, 0, stream>>>(w2, wT2, DHIDDEN, DMODEL);
  // MLP half 1: g = gelu(A3 @ w1[:, :768] + b1[:768]); out += g @ w2[:768, :] + b2
  gemm_bt_kernel<2><<<3072, b256, 0, stream>>>(A3, DMODEL, wT1, DMODEL, 0, DMODEL,
                                               b1, nullptr, gb, DINNER, 6);
  gemm_bt_kernel<1><<<1536, b256, 0, stream>>>(gb, DINNER, wT2, DHIDDEN, 0, DINNER,
                                               b2, out, out, DMODEL, 3);
  // MLP half 2: g = gelu(A3 @ w1[:, 768:] + b1[768:]); out += g @ w2[768:, :]
  gemm_bt_kernel<2><<<3072, b256, 0, stream>>>(A3, DMODEL, wT1 + (size_t)768 * DMODEL,
                                               DMODEL, 0, DMODEL, b1 + 768, nullptr,
                                               gb, DINNER, 6);
  gemm_bt_kernel<1><<<1536, b256, 0, stream>>>(gb, DINNER, wT2, DHIDDEN, 768, DINNER,
                                               nullptr, out, out, DMODEL, 3);
}

// Round 4
// 734.590 us; speedup vs baseline: 1.9104x; 1.0868x over previous
//
#include <hip/hip_runtime.h>
#include <math.h>

// LegacyVMambaBlock R4: GEMMs upgraded to 2-phase double-buffered LDS
// (stage t+1 before compute t, one barrier/K-step). MLP split by M (tokens)
// so G4 runs full K=1536. Fast sigmoid-gelu replaces erff. Weights pre-
// transposed bf16 [N][K]; fused-LN A-prep; XOR-swizzled LDS (proven R3).

typedef __attribute__((ext_vector_type(8))) short bf16x8;
typedef __attribute__((ext_vector_type(4))) float f32x4;

#define T_TOKENS 65536
#define DMODEL 384
#define DINNER 768
#define DHIDDEN 1536

__device__ __forceinline__ float bf2f(unsigned short u) {
  unsigned int x = ((unsigned int)u) << 16;
  return __builtin_bit_cast(float, x);
}
__device__ __forceinline__ unsigned short f2bf(float f) {
  unsigned int x = __builtin_bit_cast(unsigned int, f);
  x += 0x7fffu + ((x >> 16) & 1u);
  return (unsigned short)(x >> 16);
}
__device__ __forceinline__ void unpack2(unsigned int u, float& lo, float& hi) {
  lo = __builtin_bit_cast(float, u << 16);
  hi = __builtin_bit_cast(float, u & 0xffff0000u);
}
__device__ __forceinline__ unsigned int pack2(float lo, float hi) {
  return (unsigned int)f2bf(lo) | ((unsigned int)f2bf(hi) << 16);
}

__device__ __forceinline__ void gload16(const void* g, void* l) {
  __builtin_amdgcn_global_load_lds(
      (const __attribute__((address_space(1))) void*)g,
      (__attribute__((address_space(3))) void*)l, 16, 0, 0);
}

// ---------- fused LN (stats + normalize + bf16 store), one wave per token ----
__global__ __launch_bounds__(256) void ln_fused_f32_384(
    const float* __restrict__ in, const float* __restrict__ g,
    const float* __restrict__ b, unsigned short* __restrict__ out) {
  const int tok = blockIdx.x * 4 + (threadIdx.x >> 6);
  const int lane = threadIdx.x & 63;
  const float2* row = (const float2*)(in + (size_t)tok * 384);
  float2 v[3];
  float s = 0.f, ss = 0.f;
#pragma unroll
  for (int k = 0; k < 3; k++) {
    v[k] = row[lane + 64 * k];
    s += v[k].x + v[k].y;
    ss += v[k].x * v[k].x + v[k].y * v[k].y;
  }
#pragma unroll
  for (int off = 32; off > 0; off >>= 1) {
    s += __shfl_xor(s, off);
    ss += __shfl_xor(ss, off);
  }
  const float m = s * (1.0f / 384.0f);
  const float r = rsqrtf(ss * (1.0f / 384.0f) - m * m + 1e-5f);
  unsigned int* op = (unsigned int*)(out + (size_t)tok * 384);
#pragma unroll
  for (int k = 0; k < 3; k++) {
    const int c = lane + 64 * k;
    const float2 gg = ((const float2*)g)[c];
    const float2 bb = ((const float2*)b)[c];
    op[c] = pack2((v[k].x - m) * r * gg.x + bb.x, (v[k].y - m) * r * gg.y + bb.y);
  }
}

__global__ __launch_bounds__(256) void ln_fused_bf16_768(
    const unsigned short* __restrict__ in, const float* __restrict__ g,
    const float* __restrict__ b, unsigned short* __restrict__ out) {
  const int tok = blockIdx.x * 4 + (threadIdx.x >> 6);
  const int lane = threadIdx.x & 63;
  const uint2* row = (const uint2*)(in + (size_t)tok * 768);
  uint2 u[3];
  float s = 0.f, ss = 0.f;
  float e[3][4];
#pragma unroll
  for (int k = 0; k < 3; k++) {
    u[k] = row[lane + 64 * k];
    unpack2(u[k].x, e[k][0], e[k][1]);
    unpack2(u[k].y, e[k][2], e[k][3]);
#pragma unroll
    for (int j = 0; j < 4; j++) {
      s += e[k][j];
      ss += e[k][j] * e[k][j];
    }
  }
#pragma unroll
  for (int off = 32; off > 0; off >>= 1) {
    s += __shfl_xor(s, off);
    ss += __shfl_xor(ss, off);
  }
  const float m = s * (1.0f / 768.0f);
  const float r = rsqrtf(ss * (1.0f / 768.0f) - m * m + 1e-5f);
  uint2* op = (uint2*)(out + (size_t)tok * 768);
#pragma unroll
  for (int k = 0; k < 3; k++) {
    const int c = lane + 64 * k;
    const float4 gg = ((const float4*)g)[c];
    const float4 bb = ((const float4*)b)[c];
    uint2 w;
    w.x = pack2((e[k][0] - m) * r * gg.x + bb.x, (e[k][1] - m) * r * gg.y + bb.y);
    w.y = pack2((e[k][2] - m) * r * gg.z + bb.z, (e[k][3] - m) * r * gg.w + bb.w);
    op[c] = w;
  }
}

// ---------- weight prep: f32 [K,N] -> bf16 [N,K] (32x32 LDS transpose) ------
__global__ __launch_bounds__(256) void wprep_kernel(const float* __restrict__ in,
                                                    unsigned short* __restrict__ out,
                                                    int K, int N) {
  __shared__ float t[32][33];
  const int k0 = blockIdx.x * 32, n0 = blockIdx.y * 32;
  const int a = threadIdx.x & 31, b8 = threadIdx.x >> 5;
#pragma unroll
  for (int i = 0; i < 4; i++)
    t[b8 + 8 * i][a] = in[(size_t)(k0 + b8 + 8 * i) * N + n0 + a];
  __syncthreads();
#pragma unroll
  for (int i = 0; i < 4; i++)
    out[(size_t)(n0 + b8 + 8 * i) * K + k0 + a] = f2bf(t[a][b8 + 8 * i]);
}

// ---------- GEMM: C[M,:] = A[M,KT]bf16 @ Bt[N,KT]bf16^T + bias (+epi) -------
// BM=BN=128, BK=64, 4 waves 2x2. Double-buffered LDS (2x16KB per operand):
// stage tile t+1 (global_load_lds w=16) BEFORE ds_read+MFMA of tile t; one
// __syncthreads per K-step (implicit vmcnt(0) lands after compute). XOR
// swizzle phys = logical ^ ((row&7)<<4) on both sides (proven R3, 0 conflicts).
// EPI: 0 = bf16 store (+bias); 1 = f32 store (+bias+res); 2 = gelu bf16 store.
template <int EPI>
__global__ __launch_bounds__(256) void gemm_bt_kernel(
    const unsigned short* __restrict__ A, int lda,
    const unsigned short* __restrict__ Bt, int ldb, int KT,
    const float* __restrict__ bias, const float* __restrict__ res,
    void* __restrict__ C, int ldc, int nby) {
  __shared__ unsigned short As[2][8192];  // 2 x 16KB
  __shared__ unsigned short Bs[2][8192];

  const int tid = threadIdx.x;
  const int w = tid >> 6, lane = tid & 63;
  const int cpx = gridDim.x >> 3;
  const int g = blockIdx.x;
  const int sw = (g & 7) * cpx + (g >> 3);
  const int bx = sw / nby, by = sw - bx * nby;
  const int tok0 = bx << 7, n0 = by << 7;

  const int wm = w >> 1, wn = w & 1;
  const int lrow = lane & 15, kgrp = lane >> 4;
  const int cx = lrow & 7;

  const int lr8 = lane >> 3;
  const int kce = ((lane & 7) ^ lr8) << 3;  // inverse-swizzled k element offset
  const unsigned short* Abase = A + (size_t)(tok0 + w * 32 + lr8) * lda + kce;
  const unsigned short* Bbase = Bt + (size_t)(n0 + w * 32 + lr8) * ldb + kce;

  f32x4 acc[4][4];
#pragma unroll
  for (int i = 0; i < 4; i++)
#pragma unroll
    for (int j = 0; j < 4; j++) {
      f32x4 z = {0.f, 0.f, 0.f, 0.f};
      acc[i][j] = z;
    }

  const int nt = KT >> 6;
  // prologue: stage tile 0 into buf 0
#pragma unroll
  for (int i = 0; i < 4; i++) {
    gload16(Abase + (size_t)i * 8 * lda, (char*)As[0] + (w * 4 + i) * 1024);
    gload16(Bbase + (size_t)i * 8 * ldb, (char*)Bs[0] + (w * 4 + i) * 1024);
  }
  __syncthreads();

  int buf = 0;
  for (int t = 0; t < nt; t++) {
    // issue next-tile staging first (overlaps with this tile's compute)
    if (t + 1 < nt) {
      const int kt = (t + 1) << 6;
#pragma unroll
      for (int i = 0; i < 4; i++) {
        gload16(Abase + (size_t)i * 8 * lda + kt,
                (char*)As[buf ^ 1] + (w * 4 + i) * 1024);
        gload16(Bbase + (size_t)i * 8 * ldb + kt,
                (char*)Bs[buf ^ 1] + (w * 4 + i) * 1024);
      }
    }
    bf16x8 af[2][4], bf_[2][4];
#pragma unroll
    for (int ks = 0; ks < 2; ks++) {
#pragma unroll
      for (int f = 0; f < 4; f++) {
        const int co = ((ks * 4 + kgrp) ^ cx) << 4;
        af[ks][f] = *(const bf16x8*)((const char*)As[buf] +
                                     (wm * 64 + f * 16 + lrow) * 128 + co);
        bf_[ks][f] = *(const bf16x8*)((const char*)Bs[buf] +
                                      (wn * 64 + f * 16 + lrow) * 128 + co);
      }
    }
#pragma unroll
    for (int ks = 0; ks < 2; ks++)
#pragma unroll
      for (int mf = 0; mf < 4; mf++)
#pragma unroll
        for (int nf = 0; nf < 4; nf++)
          acc[mf][nf] = __builtin_amdgcn_mfma_f32_16x16x32_bf16(
              af[ks][mf], bf_[ks][nf], acc[mf][nf], 0, 0, 0);
    __syncthreads();  // vmcnt(0)+barrier: next buf ready, this buf reusable
    buf ^= 1;
  }

#pragma unroll
  for (int mf = 0; mf < 4; mf++) {
#pragma unroll
    for (int nf = 0; nf < 4; nf++) {
      const int gcol = n0 + wn * 64 + nf * 16 + lrow;
      const float bv = bias ? bias[gcol] : 0.0f;
#pragma unroll
      for (int r = 0; r < 4; r++) {
        const int grow = tok0 + wm * 64 + mf * 16 + kgrp * 4 + r;
        float v = acc[mf][nf][r] + bv;
        const size_t idx = (size_t)grow * ldc + gcol;
        if constexpr (EPI == 0) {
          ((unsigned short*)C)[idx] = f2bf(v);
        } else if constexpr (EPI == 1) {
          ((float*)C)[idx] = v + res[idx];
        } else {
          // fast gelu: v * sigmoid(1.5957691*(v + 0.044715 v^3))
          const float z = 1.5957691216057308f * (v + 0.044715f * v * v * v);
          const float gl = v / (1.0f + __expf(-z));
          ((unsigned short*)C)[idx] = f2bf(gl);
        }
      }
    }
  }
}

// ---------- depthwise 3x3 conv, 8 ch/thread ----------
__global__ __launch_bounds__(256) void dwconv_kernel(
    const unsigned short* __restrict__ p, const float* __restrict__ kw,
    unsigned short* __restrict__ out) {
  const int u = blockIdx.x * 256 + threadIdx.x;
  const int cg = u % 96;
  const int pos = u / 96;
  const int c = cg * 8;
  const int w = pos & 63;
  const int h = (pos >> 6) & 63;
  const int b = pos >> 12;

  float acc[8];
#pragma unroll
  for (int j = 0; j < 8; j++) acc[j] = 0.f;

#pragma unroll
  for (int dh = 0; dh < 3; dh++) {
    const int hh = h + dh - 1;
    const bool vh = (unsigned)hh < 64u;
    const int hcl = min(max(hh, 0), 63);
    const size_t rb = ((size_t)((b << 12) + (hcl << 6))) * DINNER + c;
#pragma unroll
    for (int dw = 0; dw < 3; dw++) {
      const int ww = w + dw - 1;
      const bool vv = vh && ((unsigned)ww < 64u);
      const int wcl = min(max(ww, 0), 63);
      uint4 pv = *(const uint4*)(p + rb + (size_t)wcl * DINNER);
      if (!vv) { pv.x = 0; pv.y = 0; pv.z = 0; pv.w = 0; }
      const float4 k0 = *(const float4*)(kw + (dh * 3 + dw) * DINNER + c);
      const float4 k1 = *(const float4*)(kw + (dh * 3 + dw) * DINNER + c + 4);
      float lo, hi;
      unpack2(pv.x, lo, hi); acc[0] += lo * k0.x; acc[1] += hi * k0.y;
      unpack2(pv.y, lo, hi); acc[2] += lo * k0.z; acc[3] += hi * k0.w;
      unpack2(pv.z, lo, hi); acc[4] += lo * k1.x; acc[5] += hi * k1.y;
      unpack2(pv.w, lo, hi); acc[6] += lo * k1.z; acc[7] += hi * k1.w;
    }
  }
  uint4 st;
  st.x = pack2(acc[0], acc[1]);
  st.y = pack2(acc[2], acc[3]);
  st.z = pack2(acc[4], acc[5]);
  st.w = pack2(acc[6], acc[7]);
  *(uint4*)(out + (size_t)pos * DINNER + c) = st;
}

// ---------- EMA scans ----------
__global__ __launch_bounds__(128) void scan_w_kernel(
    const unsigned short* __restrict__ local, unsigned short* __restrict__ out1) {
  const int c2 = blockIdx.x * 128 + threadIdx.x;
  const int bh = blockIdx.y;
  const unsigned int* lp = (const unsigned int*)(local + (size_t)bh * 64 * DINNER) + c2;
  unsigned int* op = (unsigned int*)(out1 + (size_t)bh * 64 * DINNER) + c2;
  unsigned int v2[64], f2[64];
#pragma unroll
  for (int w = 0; w < 64; w++) v2[w] = lp[w * (DINNER / 2)];
  float ya = 0.f, yb = 0.f;
#pragma unroll
  for (int w = 0; w < 64; w++) {
    float a, b;
    unpack2(v2[w], a, b);
    ya = 0.6f * ya + 0.4f * a;
    yb = 0.6f * yb + 0.4f * b;
    f2[w] = pack2(ya, yb);
  }
  ya = 0.f; yb = 0.f;
#pragma unroll
  for (int w = 63; w >= 0; w--) {
    float a, b, fa, fb;
    unpack2(v2[w], a, b);
    ya = 0.6f * ya + 0.4f * a;
    yb = 0.6f * yb + 0.4f * b;
    unpack2(f2[w], fa, fb);
    op[w * (DINNER / 2)] = pack2(a + 0.25f * (fa + ya), b + 0.25f * (fb + yb));
  }
}

__global__ __launch_bounds__(128) void scan_h_kernel(
    const unsigned short* __restrict__ local, unsigned short* inout) {
  const int c2 = blockIdx.x * 128 + threadIdx.x;
  const int bw = blockIdx.y;
  const int b = bw >> 6, w = bw & 63;
  const unsigned int base = (unsigned int)(b * 4096 + w) * (DINNER / 2) + c2;
  const unsigned int sh = 64 * (DINNER / 2);
  const unsigned int* lp = (const unsigned int*)local + base;
  unsigned int* io = (unsigned int*)inout + base;
  unsigned int v2[64], f2[64];
#pragma unroll
  for (int h = 0; h < 64; h++) v2[h] = lp[h * sh];
  float ya = 0.f, yb = 0.f;
#pragma unroll
  for (int h = 0; h < 64; h++) {
    float a, b;
    unpack2(v2[h], a, b);
    ya = 0.6f * ya + 0.4f * a;
    yb = 0.6f * yb + 0.4f * b;
    f2[h] = pack2(ya, yb);
  }
  ya = 0.f; yb = 0.f;
#pragma unroll
  for (int h = 63; h >= 0; h--) {
    float a, b, fa, fb, oa, ob;
    unpack2(v2[h], a, b);
    ya = 0.6f * ya + 0.4f * a;
    yb = 0.6f * yb + 0.4f * b;
    unpack2(f2[h], fa, fb);
    unpack2(io[h * sh], oa, ob);
    io[h * sh] = pack2(oa + 0.25f * (fa + ya), ob + 0.25f * (fb + yb));
  }
}

extern "C" void kernel_launch(void* const* d_in, const int* in_sizes, int n_in,
                              void* d_out, int out_size, void* d_ws,
                              size_t ws_size, hipStream_t stream) {
  const float* x = (const float*)d_in[0];
  const float* n1_g = (const float*)d_in[1];
  const float* n1_b = (const float*)d_in[2];
  const float* w_in = (const float*)d_in[3];
  const float* b_in = (const float*)d_in[4];
  const float* k_conv = (const float*)d_in[5];
  const float* on_g = (const float*)d_in[6];
  const float* on_b = (const float*)d_in[7];
  const float* w_out = (const float*)d_in[8];
  const float* b_out = (const float*)d_in[9];
  const float* n2_g = (const float*)d_in[10];
  const float* n2_b = (const float*)d_in[11];
  const float* w1 = (const float*)d_in[12];
  const float* b1 = (const float*)d_in[13];
  const float* w2 = (const float*)d_in[14];
  const float* b2 = (const float*)d_in[15];

  const size_t MB = 1024 * 1024;
  char* ws = (char*)d_ws;
  // proven-safe layout: 1.5MB reserved + R1 96MB + R2 96MB = 193.5MB
  unsigned short* R1 = (unsigned short*)(ws + 3 * MB / 2);
  unsigned short* R2 = (unsigned short*)(ws + 3 * MB / 2 + 96 * MB);

  unsigned short* A1 = R2;                        // 48MB
  unsigned short* wTin = R2 + (48 * MB) / 2;      // [768][384]
  unsigned short* p = R1;                         // 96MB
  unsigned short* local = R2;                     // 96MB (A1,wTin dead)
  unsigned short* mixed = R1;                     // overwrites p
  unsigned short* A2 = R2;                        // 96MB (local dead)
  unsigned short* wTout = R1;                     // [384][768] (mixed dead)
  unsigned short* A3 = R1;                        // 48MB (wTout dead after G2)
  unsigned short* wT1 = R1 + (48 * MB) / 2;       // [1536][384]
  unsigned short* wT2 = wT1 + (size_t)1536 * 384; // [384][1536]
  unsigned short* gb = R2;                        // 96MB = 32768 x 1536 bf16

  float* out = (float*)d_out;
  dim3 b256(256);

  // LN1(x) -> A1 bf16
  ln_fused_f32_384<<<T_TOKENS / 4, b256, 0, stream>>>(x, n1_g, n1_b, A1);
  wprep_kernel<<<dim3(12, 24), b256, 0, stream>>>(w_in, wTin, DMODEL, DINNER);
  // p = A1 @ w_in + b_in  (bf16)
  gemm_bt_kernel<0><<<3072, b256, 0, stream>>>(A1, DMODEL, wTin, DMODEL, DMODEL,
                                               b_in, nullptr, p, DINNER, 6);
  // local = dwconv3x3(p)
  dwconv_kernel<<<T_TOKENS * 96 / 256, b256, 0, stream>>>(p, k_conv, local);
  // mixed = local + 0.25*(lr+rl); then += 0.25*(tb+bt)
  scan_w_kernel<<<dim3(3, 1024), dim3(128), 0, stream>>>(local, mixed);
  scan_h_kernel<<<dim3(3, 1024), dim3(128), 0, stream>>>(local, mixed);
  // LN(on)(mixed) -> A2 bf16
  ln_fused_bf16_768<<<T_TOKENS / 4, b256, 0, stream>>>(mixed, on_g, on_b, A2);
  wprep_kernel<<<dim3(24, 12), b256, 0, stream>>>(w_out, wTout, DINNER, DMODEL);
  // out = x + A2 @ w_out + b_out  (f32)
  gemm_bt_kernel<1><<<1536, b256, 0, stream>>>(A2, DINNER, wTout, DINNER, DINNER,
                                               b_out, x, out, DMODEL, 3);
  // LN2(out) -> A3 bf16 (all tokens)
  ln_fused_f32_384<<<T_TOKENS / 4, b256, 0, stream>>>(out, n2_g, n2_b, A3);
  wprep_kernel<<<dim3(12, 48), b256, 0, stream>>>(w1, wT1, DMODEL, DHIDDEN);
  wprep_kernel<<<dim3(48, 12), b256, 0, stream>>>(w2, wT2, DHIDDEN, DMODEL);
  // MLP split by tokens: half hh covers 32768 tokens, full hidden 1536.
  for (int hh = 0; hh < 2; hh++) {
    const size_t toff = (size_t)hh * 32768;
    // g = gelu(A3_half @ w1 + b1)  [32768 x 1536 bf16]
    gemm_bt_kernel<2><<<3072, b256, 0, stream>>>(
        A3 + toff * DMODEL, DMODEL, wT1, DMODEL, DMODEL, b1, nullptr, gb,
        DHIDDEN, 12);
    // out_half += g @ w2 + b2  (K=1536, in-place rmw on d_out)
    gemm_bt_kernel<1><<<768, b256, 0, stream>>>(
        gb, DHIDDEN, wT2, DHIDDEN, DHIDDEN, b2, out + toff * DMODEL,
        out + toff * DMODEL, DMODEL, 3);
  }
}